// Round 1
// baseline (2284.483 us; speedup 1.0000x reference)
//
#include <hip/hip_runtime.h>

#define DIM 64
#define LN_EPS 1e-5f

// ---------------- degree / norm precompute ----------------

__global__ void k_init_deg(float* __restrict__ deg, int n) {
    int i = blockIdx.x * blockDim.x + threadIdx.x;
    if (i < n) deg[i] = 1.0f;  // self-loop
}

__global__ void k_count(const int* __restrict__ dst, float* __restrict__ deg, int e_cnt) {
    int e = blockIdx.x * blockDim.x + threadIdx.x;
    if (e < e_cnt) atomicAdd(&deg[dst[e]], 1.0f);
}

__global__ void k_rsqrt(float* __restrict__ deg, int n) {
    int i = blockIdx.x * blockDim.x + threadIdx.x;
    if (i < n) deg[i] = rsqrtf(deg[i]);
}

__global__ void k_norm(const int* __restrict__ src, const int* __restrict__ dst,
                       const float* __restrict__ dinv, float* __restrict__ norm, int e_cnt) {
    int e = blockIdx.x * blockDim.x + threadIdx.x;
    if (e < e_cnt) norm[e] = dinv[src[e]] * dinv[dst[e]];
}

// ---------------- per-layer kernels ----------------

// h = xin @ W ; agg = h * dinv^2 (self-loop contribution seeds the accumulator)
// one wave (64 lanes) per row; W staged in LDS (16 KB), 4 rows per 256-thread block.
__global__ __launch_bounds__(256) void k_gemm(const float* __restrict__ xin,
                                              const float* __restrict__ W,
                                              const float* __restrict__ dinv,
                                              float* __restrict__ h,
                                              float* __restrict__ agg, int n) {
    __shared__ float lw[DIM * DIM];
    int t = threadIdx.x;
#pragma unroll
    for (int j = 0; j < 16; j++) lw[t + 256 * j] = W[t + 256 * j];
    __syncthreads();

    int wave = t >> 6, lane = t & 63;
    int row = blockIdx.x * 4 + wave;
    if (row >= n) return;

    float xv = xin[row * DIM + lane];
    float acc = 0.f;
#pragma unroll
    for (int k = 0; k < DIM; k++) {
        float xk = __shfl(xv, k, 64);
        acc = fmaf(xk, lw[k * DIM + lane], acc);  // lane-consecutive -> conflict-free
    }
    h[row * DIM + lane] = acc;
    float di = dinv[row];
    agg[row * DIM + lane] = acc * di * di;
}

// agg[dst] += h[src] * norm[e]; 16 threads per edge, float4 gather, 4 atomics each.
__global__ __launch_bounds__(256) void k_scatter(const int* __restrict__ src,
                                                 const int* __restrict__ dst,
                                                 const float* __restrict__ norm,
                                                 const float* __restrict__ h,
                                                 float* __restrict__ agg, int e_cnt) {
    int t = blockIdx.x * blockDim.x + threadIdx.x;
    int e = t >> 4;
    if (e >= e_cnt) return;
    int l = t & 15;
    int s = src[e], d = dst[e];
    float w = norm[e];
    float4 hv = ((const float4*)(h + (size_t)s * DIM))[l];
    float* ap = agg + (size_t)d * DIM + l * 4;
    atomicAdd(ap + 0, hv.x * w);
    atomicAdd(ap + 1, hv.y * w);
    atomicAdd(ap + 2, hv.z * w);
    atomicAdd(ap + 3, hv.w * w);
}

// xout = relu(LN(agg + b) * gamma + beta); one wave per row.
__global__ __launch_bounds__(256) void k_ln(const float* __restrict__ agg,
                                            const float* __restrict__ b,
                                            const float* __restrict__ gamma,
                                            const float* __restrict__ beta,
                                            float* __restrict__ xout, int n) {
    int t = threadIdx.x;
    int wave = t >> 6, lane = t & 63;
    int row = blockIdx.x * 4 + wave;
    if (row >= n) return;

    float v = agg[row * DIM + lane] + b[lane];
    float s = v;
#pragma unroll
    for (int m = 1; m < 64; m <<= 1) s += __shfl_xor(s, m, 64);
    float mu = s * (1.0f / 64.0f);
    float dv = v - mu;
    float d2 = dv * dv;
#pragma unroll
    for (int m = 1; m < 64; m <<= 1) d2 += __shfl_xor(d2, m, 64);
    float var = d2 * (1.0f / 64.0f);
    float y = dv * rsqrtf(var + LN_EPS) * gamma[lane] + beta[lane];
    xout[row * DIM + lane] = fmaxf(y, 0.f);
}

// ---------------- launch ----------------

extern "C" void kernel_launch(void* const* d_in, const int* in_sizes, int n_in,
                              void* d_out, int out_size, void* d_ws, size_t ws_size,
                              hipStream_t stream) {
    const float* x      = (const float*)d_in[0];
    const int*   ei     = (const int*)  d_in[1];
    const float* Ws     = (const float*)d_in[2];
    const float* bs     = (const float*)d_in[3];
    const float* gammas = (const float*)d_in[4];
    const float* betas  = (const float*)d_in[5];
    float* out = (float*)d_out;

    int n = in_sizes[0] / DIM;
    int E = in_sizes[1] / 2;
    int n_layers = in_sizes[2] / (DIM * DIM);

    const int* srcp = ei;
    const int* dstp = ei + E;

    // workspace layout (floats): dinv[n] | norm[E] | h[n*64] | agg[n*64]
    float* dinv = (float*)d_ws;
    float* norm = dinv + n;
    float* h    = norm + E;
    float* agg  = h + (size_t)n * DIM;

    k_init_deg<<<(n + 255) / 256, 256, 0, stream>>>(dinv, n);
    k_count  <<<(E + 255) / 256, 256, 0, stream>>>(dstp, dinv, E);
    k_rsqrt  <<<(n + 255) / 256, 256, 0, stream>>>(dinv, n);
    k_norm   <<<(E + 255) / 256, 256, 0, stream>>>(srcp, dstp, dinv, norm, E);

    for (int i = 0; i < n_layers; i++) {
        const float* xin = (i == 0) ? x : out;
        k_gemm   <<<(n + 3) / 4, 256, 0, stream>>>(xin, Ws + (size_t)i * DIM * DIM, dinv, h, agg, n);
        k_scatter<<<(E * 16 + 255) / 256, 256, 0, stream>>>(srcp, dstp, norm, h, agg, E);
        k_ln     <<<(n + 3) / 4, 256, 0, stream>>>(agg, bs + (size_t)i * DIM,
                                                   gammas + (size_t)i * DIM,
                                                   betas + (size_t)i * DIM, out, n);
    }
}

// Round 2
// 480.557 us; speedup vs baseline: 4.7538x; 4.7538x over previous
//
#include <hip/hip_runtime.h>

#define DIM 64
#define LN_EPS 1e-5f

// ---------------- CSR build (once per call) ----------------

__global__ void k_zero(int* __restrict__ deg, int* __restrict__ counter, int n) {
    int i = blockIdx.x * blockDim.x + threadIdx.x;
    if (i < n) deg[i] = 0;
    if (i == 0) { counter[0] = 0; counter[1] = 0; }
}

__global__ void k_count(const int* __restrict__ dst, int* __restrict__ deg, int e_cnt) {
    int e = blockIdx.x * blockDim.x + threadIdx.x;
    if (e < e_cnt) atomicAdd(&deg[dst[e]], 1);
}

// reserve a contiguous CSR segment per row (order across rows irrelevant);
// also compute dinv = rsqrt(deg + 1 self-loop).
__global__ void k_reserve(const int* __restrict__ deg, int* __restrict__ rowstart,
                          int* __restrict__ cursor, float* __restrict__ dinv,
                          int* __restrict__ counter, int n) {
    int i = blockIdx.x * blockDim.x + threadIdx.x;
    if (i >= n) return;
    int d = deg[i];
    int s = atomicAdd(counter, d);
    rowstart[i] = s;
    cursor[i] = s;
    dinv[i] = rsqrtf((float)(d + 1));
}

// csr[pos] = (src, norm) packed as int2 -> one 8B load per edge in the gather.
__global__ void k_fill(const int* __restrict__ src, const int* __restrict__ dst,
                       const float* __restrict__ dinv, int* __restrict__ cursor,
                       int2* __restrict__ csr, int e_cnt) {
    int e = blockIdx.x * blockDim.x + threadIdx.x;
    if (e >= e_cnt) return;
    int s = src[e], d = dst[e];
    int pos = atomicAdd(&cursor[d], 1);
    float w = dinv[s] * dinv[d];
    csr[pos] = make_int2(s, __float_as_int(w));
}

// ---------------- per-layer kernels ----------------

// h = xin @ W ; one wave (64 lanes) per row; W staged in LDS.
__global__ __launch_bounds__(256) void k_gemm(const float* __restrict__ xin,
                                              const float* __restrict__ W,
                                              float* __restrict__ h, int n) {
    __shared__ float lw[DIM * DIM];
    int t = threadIdx.x;
#pragma unroll
    for (int j = 0; j < 16; j++) lw[t + 256 * j] = W[t + 256 * j];
    __syncthreads();

    int wave = t >> 6, lane = t & 63;
    int row = blockIdx.x * 4 + wave;
    if (row >= n) return;

    float xv = xin[row * DIM + lane];
    float acc = 0.f;
#pragma unroll
    for (int k = 0; k < DIM; k++) {
        float xk = __shfl(xv, k, 64);
        acc = fmaf(xk, lw[k * DIM + lane], acc);  // lane-consecutive -> conflict-free
    }
    h[row * DIM + lane] = acc;
}

// Fused: CSR gather-aggregate (+ self loop) + bias + LayerNorm + ReLU.
// One wave per dst row, lane = feature.
__global__ __launch_bounds__(256) void k_aggln(const int* __restrict__ rowstart,
                                               const int* __restrict__ deg,
                                               const float* __restrict__ dinv,
                                               const int2* __restrict__ csr,
                                               const float* __restrict__ h,
                                               const float* __restrict__ b,
                                               const float* __restrict__ gamma,
                                               const float* __restrict__ beta,
                                               float* __restrict__ xout, int n) {
    int t = threadIdx.x;
    int wave = t >> 6, lane = t & 63;
    int row = blockIdx.x * 4 + wave;
    if (row >= n) return;

    float di = dinv[row];
    float acc = h[(size_t)row * DIM + lane] * di * di;  // self-loop term

    int s0 = rowstart[row];
    int cnt = deg[row];
    int i = 0;
    for (; i + 2 <= cnt; i += 2) {  // unroll-by-2: overlap the two edge fetches
        int2 e0 = csr[s0 + i];
        int2 e1 = csr[s0 + i + 1];
        float h0 = h[(size_t)e0.x * DIM + lane];
        float h1 = h[(size_t)e1.x * DIM + lane];
        acc = fmaf(__int_as_float(e0.y), h0, acc);
        acc = fmaf(__int_as_float(e1.y), h1, acc);
    }
    if (i < cnt) {
        int2 e0 = csr[s0 + i];
        acc = fmaf(__int_as_float(e0.y), h[(size_t)e0.x * DIM + lane], acc);
    }

    // bias + LayerNorm + ReLU
    float v = acc + b[lane];
    float s = v;
#pragma unroll
    for (int m = 1; m < 64; m <<= 1) s += __shfl_xor(s, m, 64);
    float mu = s * (1.0f / 64.0f);
    float dv = v - mu;
    float d2 = dv * dv;
#pragma unroll
    for (int m = 1; m < 64; m <<= 1) d2 += __shfl_xor(d2, m, 64);
    float var = d2 * (1.0f / 64.0f);
    float y = dv * rsqrtf(var + LN_EPS) * gamma[lane] + beta[lane];
    xout[(size_t)row * DIM + lane] = fmaxf(y, 0.f);
}

// ---------------- launch ----------------

extern "C" void kernel_launch(void* const* d_in, const int* in_sizes, int n_in,
                              void* d_out, int out_size, void* d_ws, size_t ws_size,
                              hipStream_t stream) {
    const float* x      = (const float*)d_in[0];
    const int*   ei     = (const int*)  d_in[1];
    const float* Ws     = (const float*)d_in[2];
    const float* bs     = (const float*)d_in[3];
    const float* gammas = (const float*)d_in[4];
    const float* betas  = (const float*)d_in[5];
    float* out = (float*)d_out;

    int n = in_sizes[0] / DIM;
    int E = in_sizes[1] / 2;
    int n_layers = in_sizes[2] / (DIM * DIM);

    const int* srcp = ei;
    const int* dstp = ei + E;

    // workspace layout: deg[n] | rowstart[n] | cursor[n] | dinv[n] | counter[2] | csr[E] (int2) | h[n*64]
    int* deg      = (int*)d_ws;
    int* rowstart = deg + n;
    int* cursor   = rowstart + n;
    float* dinv   = (float*)(cursor + n);
    int* counter  = (int*)(dinv + n);
    int2* csr     = (int2*)(counter + 2);   // 8B-aligned: 4*4n+8 bytes before it
    float* h      = (float*)(csr + E);

    int nb_n = (n + 255) / 256;
    int nb_e = (E + 255) / 256;

    k_zero   <<<nb_n, 256, 0, stream>>>(deg, counter, n);
    k_count  <<<nb_e, 256, 0, stream>>>(dstp, deg, E);
    k_reserve<<<nb_n, 256, 0, stream>>>(deg, rowstart, cursor, dinv, counter, n);
    k_fill   <<<nb_e, 256, 0, stream>>>(srcp, dstp, dinv, cursor, csr, E);

    for (int i = 0; i < n_layers; i++) {
        const float* xin = (i == 0) ? x : out;
        k_gemm <<<(n + 3) / 4, 256, 0, stream>>>(xin, Ws + (size_t)i * DIM * DIM, h, n);
        k_aggln<<<(n + 3) / 4, 256, 0, stream>>>(rowstart, deg, dinv, csr, h,
                                                 bs + (size_t)i * DIM,
                                                 gammas + (size_t)i * DIM,
                                                 betas + (size_t)i * DIM, out, n);
    }
}

// Round 3
// 320.013 us; speedup vs baseline: 7.1387x; 1.5017x over previous
//
#include <hip/hip_runtime.h>

#define DIM 64
#define LN_EPS 1e-5f

// ---------------- CSR build (once per call) ----------------

__global__ void k_zero(int* __restrict__ deg, int* __restrict__ counter, int n) {
    int i = blockIdx.x * blockDim.x + threadIdx.x;
    if (i < n) deg[i] = 0;
    if (i == 0) { counter[0] = 0; counter[1] = 0; }
}

__global__ void k_count(const int* __restrict__ dst, int* __restrict__ deg, int e_cnt) {
    int e = blockIdx.x * blockDim.x + threadIdx.x;
    if (e < e_cnt) atomicAdd(&deg[dst[e]], 1);
}

__global__ void k_reserve(const int* __restrict__ deg, int* __restrict__ rowstart,
                          int* __restrict__ cursor, float* __restrict__ dinv,
                          int* __restrict__ counter, int n) {
    int i = blockIdx.x * blockDim.x + threadIdx.x;
    if (i >= n) return;
    int d = deg[i];
    int s = atomicAdd(counter, d);
    rowstart[i] = s;
    cursor[i] = s;
    dinv[i] = rsqrtf((float)(d + 1));
}

__global__ void k_fill(const int* __restrict__ src, const int* __restrict__ dst,
                       const float* __restrict__ dinv, int* __restrict__ cursor,
                       int2* __restrict__ csr, int e_cnt) {
    int e = blockIdx.x * blockDim.x + threadIdx.x;
    if (e >= e_cnt) return;
    int s = src[e], d = dst[e];
    int pos = atomicAdd(&cursor[d], 1);
    float w = dinv[s] * dinv[d];
    csr[pos] = make_int2(s, __float_as_int(w));
}

// ---------------- per-layer kernels ----------------

// agg[row] = dinv^2 * xin[row] + sum_e norm_e * xin[src_e]  (aggregate-first)
// one wave per row, lane = feature; unroll 4 for load ILP.
__global__ __launch_bounds__(256) void k_agg(const int* __restrict__ rowstart,
                                             const int* __restrict__ deg,
                                             const float* __restrict__ dinv,
                                             const int2* __restrict__ csr,
                                             const float* __restrict__ xin,
                                             float* __restrict__ agg, int n) {
    int t = threadIdx.x;
    int wave = t >> 6, lane = t & 63;
    int row = blockIdx.x * 4 + wave;
    if (row >= n) return;

    float di = dinv[row];
    float acc = xin[(size_t)row * DIM + lane] * di * di;  // self-loop

    int s0 = rowstart[row];
    int cnt = deg[row];
    int i = 0;
    for (; i + 4 <= cnt; i += 4) {
        int2 e0 = csr[s0 + i + 0];
        int2 e1 = csr[s0 + i + 1];
        int2 e2 = csr[s0 + i + 2];
        int2 e3 = csr[s0 + i + 3];
        float h0 = xin[(size_t)e0.x * DIM + lane];
        float h1 = xin[(size_t)e1.x * DIM + lane];
        float h2 = xin[(size_t)e2.x * DIM + lane];
        float h3 = xin[(size_t)e3.x * DIM + lane];
        acc = fmaf(__int_as_float(e0.y), h0, acc);
        acc = fmaf(__int_as_float(e1.y), h1, acc);
        acc = fmaf(__int_as_float(e2.y), h2, acc);
        acc = fmaf(__int_as_float(e3.y), h3, acc);
    }
    for (; i < cnt; i++) {
        int2 e0 = csr[s0 + i];
        acc = fmaf(__int_as_float(e0.y), xin[(size_t)e0.x * DIM + lane], acc);
    }
    agg[(size_t)row * DIM + lane] = acc;
}

// Fused: out = relu(LN(agg @ W + b) * gamma + beta)
// Block = 256 threads = 64 rows/tile. W (64x64) + x-tile (64x68 padded) in LDS.
// Each lane: 4 rows x 4 cols register tile. LN via shfl_xor over 16-lane groups.
#define XS_STRIDE 68
__global__ __launch_bounds__(256) void k_gemmln(const float* __restrict__ agg,
                                                const float* __restrict__ W,
                                                const float* __restrict__ b,
                                                const float* __restrict__ gamma,
                                                const float* __restrict__ beta,
                                                float* __restrict__ out, int n) {
    __shared__ float ws[DIM * DIM];
    __shared__ float xs[64 * XS_STRIDE];
    int t = threadIdx.x;
    int base = blockIdx.x * 64;

    {   // stage W: 4096 floats, float4-coalesced
        const float4* W4 = (const float4*)W;
        float4* ws4 = (float4*)ws;
#pragma unroll
        for (int i = 0; i < 4; i++) ws4[t + 256 * i] = W4[t + 256 * i];
    }
    {   // stage x-tile with padded stride
        const float4* a4 = (const float4*)(agg + (size_t)base * DIM);
#pragma unroll
        for (int i = 0; i < 4; i++) {
            int f = t + 256 * i;       // float4 index in tile, 0..1023
            int r = f >> 4;            // row 0..63
            int c = f & 15;            // float4-col 0..15
            if (base + r < n)
                *(float4*)(xs + r * XS_STRIDE + c * 4) = a4[f];
        }
    }
    __syncthreads();

    int wave = t >> 6, l = t & 63;
    int rgrp = l >> 4;                 // 0..3
    int c4 = l & 15;                   // col group (4 cols)
    int row0 = wave * 16 + rgrp * 4;   // local row base (4 rows: row0..row0+3)

    float4 acc[4];
#pragma unroll
    for (int j = 0; j < 4; j++) acc[j] = make_float4(0.f, 0.f, 0.f, 0.f);

    for (int kc = 0; kc < 16; kc++) {
        float4 w0 = *(const float4*)(ws + (4 * kc + 0) * DIM + c4 * 4);
        float4 w1 = *(const float4*)(ws + (4 * kc + 1) * DIM + c4 * 4);
        float4 w2 = *(const float4*)(ws + (4 * kc + 2) * DIM + c4 * 4);
        float4 w3 = *(const float4*)(ws + (4 * kc + 3) * DIM + c4 * 4);
#pragma unroll
        for (int j = 0; j < 4; j++) {
            float4 xv = *(const float4*)(xs + (row0 + j) * XS_STRIDE + kc * 4);
            acc[j].x = fmaf(xv.x, w0.x, acc[j].x);
            acc[j].y = fmaf(xv.x, w0.y, acc[j].y);
            acc[j].z = fmaf(xv.x, w0.z, acc[j].z);
            acc[j].w = fmaf(xv.x, w0.w, acc[j].w);
            acc[j].x = fmaf(xv.y, w1.x, acc[j].x);
            acc[j].y = fmaf(xv.y, w1.y, acc[j].y);
            acc[j].z = fmaf(xv.y, w1.z, acc[j].z);
            acc[j].w = fmaf(xv.y, w1.w, acc[j].w);
            acc[j].x = fmaf(xv.z, w2.x, acc[j].x);
            acc[j].y = fmaf(xv.z, w2.y, acc[j].y);
            acc[j].z = fmaf(xv.z, w2.z, acc[j].z);
            acc[j].w = fmaf(xv.z, w2.w, acc[j].w);
            acc[j].x = fmaf(xv.w, w3.x, acc[j].x);
            acc[j].y = fmaf(xv.w, w3.y, acc[j].y);
            acc[j].z = fmaf(xv.w, w3.z, acc[j].z);
            acc[j].w = fmaf(xv.w, w3.w, acc[j].w);
        }
    }

    // epilogue: bias + LN + relu
    float4 b4 = *(const float4*)(b + c4 * 4);
    float4 g4 = *(const float4*)(gamma + c4 * 4);
    float4 be4 = *(const float4*)(beta + c4 * 4);
#pragma unroll
    for (int j = 0; j < 4; j++) {
        float4 v = make_float4(acc[j].x + b4.x, acc[j].y + b4.y,
                               acc[j].z + b4.z, acc[j].w + b4.w);
        float s = v.x + v.y + v.z + v.w;
        s += __shfl_xor(s, 1, 64);
        s += __shfl_xor(s, 2, 64);
        s += __shfl_xor(s, 4, 64);
        s += __shfl_xor(s, 8, 64);
        float mu = s * (1.0f / 64.0f);
        float4 d = make_float4(v.x - mu, v.y - mu, v.z - mu, v.w - mu);
        float q = d.x * d.x + d.y * d.y + d.z * d.z + d.w * d.w;
        q += __shfl_xor(q, 1, 64);
        q += __shfl_xor(q, 2, 64);
        q += __shfl_xor(q, 4, 64);
        q += __shfl_xor(q, 8, 64);
        float rstd = rsqrtf(q * (1.0f / 64.0f) + LN_EPS);
        float4 y = make_float4(fmaxf(fmaf(d.x * rstd, g4.x, be4.x), 0.f),
                               fmaxf(fmaf(d.y * rstd, g4.y, be4.y), 0.f),
                               fmaxf(fmaf(d.z * rstd, g4.z, be4.z), 0.f),
                               fmaxf(fmaf(d.w * rstd, g4.w, be4.w), 0.f));
        int grow = base + row0 + j;
        if (grow < n)
            *(float4*)(out + (size_t)grow * DIM + c4 * 4) = y;
    }
}

// ---------------- launch ----------------

extern "C" void kernel_launch(void* const* d_in, const int* in_sizes, int n_in,
                              void* d_out, int out_size, void* d_ws, size_t ws_size,
                              hipStream_t stream) {
    const float* x      = (const float*)d_in[0];
    const int*   ei     = (const int*)  d_in[1];
    const float* Ws     = (const float*)d_in[2];
    const float* bs     = (const float*)d_in[3];
    const float* gammas = (const float*)d_in[4];
    const float* betas  = (const float*)d_in[5];
    float* out = (float*)d_out;

    int n = in_sizes[0] / DIM;
    int E = in_sizes[1] / 2;
    int n_layers = in_sizes[2] / (DIM * DIM);

    const int* srcp = ei;
    const int* dstp = ei + E;

    // ws: deg[n] | rowstart[n] | cursor[n] | dinv[n] | counter[2] | csr[E] int2 | agg[n*64]
    int* deg      = (int*)d_ws;
    int* rowstart = deg + n;
    int* cursor   = rowstart + n;
    float* dinv   = (float*)(cursor + n);
    int* counter  = (int*)(dinv + n);
    int2* csr     = (int2*)(counter + 2);
    float* agg    = (float*)(csr + E);

    int nb_n = (n + 255) / 256;
    int nb_e = (E + 255) / 256;

    k_zero   <<<nb_n, 256, 0, stream>>>(deg, counter, n);
    k_count  <<<nb_e, 256, 0, stream>>>(dstp, deg, E);
    k_reserve<<<nb_n, 256, 0, stream>>>(deg, rowstart, cursor, dinv, counter, n);
    k_fill   <<<nb_e, 256, 0, stream>>>(srcp, dstp, dinv, cursor, csr, E);

    int nb_tile = (n + 63) / 64;
    for (int i = 0; i < n_layers; i++) {
        const float* xin = (i == 0) ? x : out;
        k_agg   <<<(n + 3) / 4, 256, 0, stream>>>(rowstart, deg, dinv, csr, xin, agg, n);
        k_gemmln<<<nb_tile, 256, 0, stream>>>(agg, Ws + (size_t)i * DIM * DIM,
                                              bs + (size_t)i * DIM,
                                              gammas + (size_t)i * DIM,
                                              betas + (size_t)i * DIM, out, n);
    }
}